// Round 1
// baseline (685.025 us; speedup 1.0000x reference)
//
#include <hip/hip_runtime.h>

// SRM neuron: per-row 50-tap 'same' conv -> threshold -> refractory scan.
// B=4096 rows, T=16384. One wave (64 lanes) per row, R=8 timesteps per lane,
// 32 blocks of 512 steps per row. Refractory scan via 4-state transfer-map
// composition across lanes (Hillis-Steele over packed 2-bit maps).

#define TLEN  16384
#define NROWS 4096
#define BLK   512
#define NBLK  32      // TLEN / BLK
#define KLEN  50
#define WPB   4       // waves per block

// compose: r[s] = then[first[s]]  (apply `first`, then `then`)
__device__ __forceinline__ int map_compose(int first, int then) {
    int r = 0;
#pragma unroll
    for (int s = 0; s < 4; ++s) {
        int a = (first >> (2 * s)) & 3;
        int b = (then >> (2 * a)) & 3;
        r |= b << (2 * s);
    }
    return r;
}

__global__ __launch_bounds__(256, 4)
void srm_kernel(const float* __restrict__ I,
                const float* __restrict__ p_tau_m,
                const float* __restrict__ p_tau_s,
                const float* __restrict__ p_v_th,
                const float* __restrict__ p_v_reset,
                float* __restrict__ out)
{
    const int lane = threadIdx.x & 63;
    const int wid  = threadIdx.x >> 6;
    const int row  = blockIdx.x * WPB + wid;

    const float tau_m   = p_tau_m[0];
    const float tau_s   = p_tau_s[0];
    const float v_th    = p_v_th[0];
    const float v_reset = p_v_reset[0];

    // Normalized taps, computed redundantly per thread (once), fully unrolled
    // so kt[] stays in registers. Matches reference fp32 construction:
    // k[t] = exp(-t/tau_m) - exp(-t/tau_s); k /= (sum(k) + 1e-10).
    float kt[KLEN];
    float ksum = 0.0f;
#pragma unroll
    for (int t = 0; t < KLEN; ++t) {
        float ft = (float)t;
        kt[t] = expf(-ft / tau_m) - expf(-ft / tau_s);
        ksum += kt[t];
    }
    ksum += 1e-10f;
#pragma unroll
    for (int t = 0; t < KLEN; ++t) kt[t] /= ksum;

    const float* Irow = I + (size_t)row * TLEN;
    float* Orow = out + (size_t)row * TLEN;

    // Rotating register sets: Pv = prev 512-block, Cv = current, Nv = next.
    float Pv[8], Cv[8], Nv[8];
#pragma unroll
    for (int j = 0; j < 8; ++j) Pv[j] = 0.0f;   // x[t<0] = 0

    {
        const float4* s0 = (const float4*)(Irow + 0 * BLK + 8 * lane);
        float4 a = s0[0], b = s0[1];
        Cv[0] = a.x; Cv[1] = a.y; Cv[2] = a.z; Cv[3] = a.w;
        Cv[4] = b.x; Cv[5] = b.y; Cv[6] = b.z; Cv[7] = b.w;
        const float4* s1 = (const float4*)(Irow + 1 * BLK + 8 * lane);
        float4 c = s1[0], d = s1[1];
        Nv[0] = c.x; Nv[1] = c.y; Nv[2] = c.z; Nv[3] = c.w;
        Nv[4] = d.x; Nv[5] = d.y; Nv[6] = d.z; Nv[7] = d.w;
    }

    // bpermute byte-addresses for neighbor-lane gathers (q = lane shift)
    const int addr_m4 = ((lane - 4) & 63) << 2;
    const int addr_m3 = ((lane - 3) & 63) << 2;
    const int addr_m2 = ((lane - 2) & 63) << 2;
    const int addr_m1 = ((lane - 1) & 63) << 2;
    const int addr_p1 = ((lane + 1) & 63) << 2;
    const int addr_p2 = ((lane + 2) & 63) << 2;
    const int addr_p3 = ((lane + 3) & 63) << 2;

    int r0 = 0;  // wave-uniform refractory state entering this block

    for (int b = 0; b < NBLK; ++b) {
        // ---- prefetch block b+2 (zeros past the end) ----
        float Lv[8];
        if (b + 2 < NBLK) {
            const float4* sl = (const float4*)(Irow + (size_t)(b + 2) * BLK + 8 * lane);
            float4 a = sl[0], c = sl[1];
            Lv[0] = a.x; Lv[1] = a.y; Lv[2] = a.z; Lv[3] = a.w;
            Lv[4] = c.x; Lv[5] = c.y; Lv[6] = c.z; Lv[7] = c.w;
        } else {
#pragma unroll
            for (int j = 0; j < 8; ++j) Lv[j] = 0.0f;
        }

        // ---- convolution: out[k] = sum_j kt[j] * x[t0+8l+k+24-j] ----
        float acc[8];
#pragma unroll
        for (int k = 0; k < 8; ++k) acc[k] = 0.0f;

#pragma unroll
        for (int o = -25; o <= 31; ++o) {      // window offset rel. to t0+8l
            const int q = o >> 3;              // lane shift (arith shr = floor)
            const int j = o & 7;               // register within set
            float w;
            if (q == 0) {
                w = Cv[j];
            } else if (q < 0) {
                // source lanes >= 64+q must supply prev-block values
                float src = (lane >= 64 + q) ? Pv[j] : Cv[j];
                int addr = (q == -4) ? addr_m4 : (q == -3) ? addr_m3
                         : (q == -2) ? addr_m2 : addr_m1;
                w = __int_as_float(__builtin_amdgcn_ds_bpermute(addr, __float_as_int(src)));
            } else {
                // source lanes < q must supply next-block values
                float src = (lane < q) ? Nv[j] : Cv[j];
                int addr = (q == 1) ? addr_p1 : (q == 2) ? addr_p2 : addr_p3;
                w = __int_as_float(__builtin_amdgcn_ds_bpermute(addr, __float_as_int(src)));
            }
#pragma unroll
            for (int k = 0; k < 8; ++k) {
                const int jj = k + 24 - o;
                if (jj >= 0 && jj < KLEN)
                    acc[k] = fmaf(kt[jj], w, acc[k]);
            }
        }

        // ---- candidates (exact reference arithmetic) ----
        const int tb = b * BLK + 8 * lane;
        int cand[8];
#pragma unroll
        for (int k = 0; k < 8; ++k) {
            float vfree = v_reset + acc[k] / 100.0f;   // true IEEE divide
            cand[k] = (vfree >= v_th) ? 1 : 0;
        }
        cand[0] &= (tb != 0);   // spikes[0] forced 0 (loop starts at t=1)

        // ---- per-lane 8-step transfer map for incoming ref in {0,1,2,3} ----
        int s0 = 0, s1 = 1, s2 = 2, s3 = 3;
#pragma unroll
        for (int k = 0; k < 8; ++k) {
            const int c3 = cand[k] ? 3 : 0;
            s0 = (s0 > 0) ? (s0 - 1) : c3;
            s1 = (s1 > 0) ? (s1 - 1) : c3;
            s2 = (s2 > 0) ? (s2 - 1) : c3;
            s3 = (s3 > 0) ? (s3 - 1) : c3;
        }
        int P = s0 | (s1 << 2) | (s2 << 4) | (s3 << 6);

        // ---- inclusive prefix composition across 64 lanes ----
#pragma unroll
        for (int d = 1; d < 64; d <<= 1) {
            const int prev = __shfl_up(P, d, 64);
            const int comp = map_compose(prev, P);
            P = (lane >= d) ? comp : P;
        }
        const int Pprev = __shfl_up(P, 1, 64);
        const int sin0  = (lane == 0) ? r0 : ((Pprev >> (2 * r0)) & 3);
        const int Pfull = __shfl(P, 63, 64);
        r0 = (Pfull >> (2 * r0)) & 3;   // carry to next 512-block

        // ---- replay with true incoming state, emit spikes ----
        int s = sin0;
        float sp[8];
#pragma unroll
        for (int k = 0; k < 8; ++k) {
            const int spike = (s == 0) & cand[k];
            sp[k] = spike ? 1.0f : 0.0f;
            s = (s > 0) ? (s - 1) : (cand[k] ? 3 : 0);
        }
        float4 o0, o1;
        o0.x = sp[0]; o0.y = sp[1]; o0.z = sp[2]; o0.w = sp[3];
        o1.x = sp[4]; o1.y = sp[5]; o1.z = sp[6]; o1.w = sp[7];
        float4* dst = (float4*)(Orow + tb);
        dst[0] = o0; dst[1] = o1;

        // ---- rotate register sets ----
#pragma unroll
        for (int j = 0; j < 8; ++j) { Pv[j] = Cv[j]; Cv[j] = Nv[j]; Nv[j] = Lv[j]; }
    }
}

extern "C" void kernel_launch(void* const* d_in, const int* in_sizes, int n_in,
                              void* d_out, int out_size, void* d_ws, size_t ws_size,
                              hipStream_t stream) {
    const float* I       = (const float*)d_in[0];
    const float* tau_m   = (const float*)d_in[1];
    const float* tau_s   = (const float*)d_in[2];
    const float* v_th    = (const float*)d_in[3];
    const float* v_reset = (const float*)d_in[4];
    float* out = (float*)d_out;

    srm_kernel<<<dim3(NROWS / WPB), dim3(256), 0, stream>>>(
        I, tau_m, tau_s, v_th, v_reset, out);
}

// Round 2
// 450.497 us; speedup vs baseline: 1.5206x; 1.5206x over previous
//
#include <hip/hip_runtime.h>

// SRM neuron: per-row 50-tap 'same' conv -> threshold -> refractory scan.
// B=4096 rows, T=16384. One wave (64 lanes) per row, 8 timesteps/lane,
// 32 blocks of 512 steps per row.
// R2: taps forced into SGPRs via readfirstlane (kills R1's scratch spills);
//     ballot fast-path skips the transfer-map scan when a 512-block has no
//     threshold crossings (~always, at 4.7 sigma).

#define TLEN  16384
#define NROWS 4096
#define BLK   512
#define NBLK  32      // TLEN / BLK
#define KLEN  50
#define WPB   4       // waves per block

__device__ __forceinline__ float uniformf(float x) {
    return __int_as_float(__builtin_amdgcn_readfirstlane(__float_as_int(x)));
}

// compose: r[s] = then[first[s]]  (apply `first`, then `then`)
__device__ __forceinline__ int map_compose(int first, int then) {
    int r = 0;
#pragma unroll
    for (int s = 0; s < 4; ++s) {
        int a = (first >> (2 * s)) & 3;
        int b = (then >> (2 * a)) & 3;
        r |= b << (2 * s);
    }
    return r;
}

__global__ __launch_bounds__(256, 4)
void srm_kernel(const float* __restrict__ I,
                const float* __restrict__ p_tau_m,
                const float* __restrict__ p_tau_s,
                const float* __restrict__ p_v_th,
                const float* __restrict__ p_v_reset,
                float* __restrict__ out)
{
    const int lane = threadIdx.x & 63;
    const int wid  = threadIdx.x >> 6;
    const int row  = blockIdx.x * WPB + wid;

    const float tau_m   = p_tau_m[0];
    const float tau_s   = p_tau_s[0];
    const float v_th    = p_v_th[0];
    const float v_reset = p_v_reset[0];

    // Taps: same arithmetic as R1 (passed bit-exact), but every value is
    // pinned wave-uniform via readfirstlane so the register allocator can
    // keep all 50 in SGPRs (VALU FMA reads them as the scalar operand).
    float ku[KLEN];
    float ksum = 0.0f;
#pragma unroll
    for (int t = 0; t < KLEN; ++t) {
        float ft = (float)t;
        float v = expf(-ft / tau_m) - expf(-ft / tau_s);
        ksum += v;
        ku[t] = uniformf(v);
    }
    const float kden = uniformf(ksum + 1e-10f);
    float kt[KLEN];
#pragma unroll
    for (int t = 0; t < KLEN; ++t) kt[t] = uniformf(ku[t] / kden);

    const float* Irow = I + (size_t)row * TLEN;
    float* Orow = out + (size_t)row * TLEN;

    // Rotating register sets: Pv = prev 512-block, Cv = current, Nv = next.
    float Pv[8], Cv[8], Nv[8];
#pragma unroll
    for (int j = 0; j < 8; ++j) Pv[j] = 0.0f;   // x[t<0] = 0

    {
        const float4* s0 = (const float4*)(Irow + 0 * BLK + 8 * lane);
        float4 a = s0[0], b = s0[1];
        Cv[0] = a.x; Cv[1] = a.y; Cv[2] = a.z; Cv[3] = a.w;
        Cv[4] = b.x; Cv[5] = b.y; Cv[6] = b.z; Cv[7] = b.w;
        const float4* s1 = (const float4*)(Irow + 1 * BLK + 8 * lane);
        float4 c = s1[0], d = s1[1];
        Nv[0] = c.x; Nv[1] = c.y; Nv[2] = c.z; Nv[3] = c.w;
        Nv[4] = d.x; Nv[5] = d.y; Nv[6] = d.z; Nv[7] = d.w;
    }

    // bpermute byte-addresses for neighbor-lane gathers (q = lane shift)
    const int addr_m4 = ((lane - 4) & 63) << 2;
    const int addr_m3 = ((lane - 3) & 63) << 2;
    const int addr_m2 = ((lane - 2) & 63) << 2;
    const int addr_m1 = ((lane - 1) & 63) << 2;
    const int addr_p1 = ((lane + 1) & 63) << 2;
    const int addr_p2 = ((lane + 2) & 63) << 2;
    const int addr_p3 = ((lane + 3) & 63) << 2;

    int r0 = 0;  // wave-uniform refractory state entering this block

    for (int b = 0; b < NBLK; ++b) {
        // ---- prefetch block b+2 (zeros past the end) ----
        float Lv[8];
        if (b + 2 < NBLK) {
            const float4* sl = (const float4*)(Irow + (size_t)(b + 2) * BLK + 8 * lane);
            float4 a = sl[0], c = sl[1];
            Lv[0] = a.x; Lv[1] = a.y; Lv[2] = a.z; Lv[3] = a.w;
            Lv[4] = c.x; Lv[5] = c.y; Lv[6] = c.z; Lv[7] = c.w;
        } else {
#pragma unroll
            for (int j = 0; j < 8; ++j) Lv[j] = 0.0f;
        }

        // ---- convolution: out[k] = sum_j kt[j] * x[t0+8l+k+24-j] ----
        float acc[8];
#pragma unroll
        for (int k = 0; k < 8; ++k) acc[k] = 0.0f;

#pragma unroll
        for (int o = -25; o <= 31; ++o) {      // window offset rel. to t0+8l
            const int q = o >> 3;              // lane shift (arith shr = floor)
            const int j = o & 7;               // register within set
            float w;
            if (q == 0) {
                w = Cv[j];
            } else if (q < 0) {
                // source lanes >= 64+q must supply prev-block values
                float src = (lane >= 64 + q) ? Pv[j] : Cv[j];
                int addr = (q == -4) ? addr_m4 : (q == -3) ? addr_m3
                         : (q == -2) ? addr_m2 : addr_m1;
                w = __int_as_float(__builtin_amdgcn_ds_bpermute(addr, __float_as_int(src)));
            } else {
                // source lanes < q must supply next-block values
                float src = (lane < q) ? Nv[j] : Cv[j];
                int addr = (q == 1) ? addr_p1 : (q == 2) ? addr_p2 : addr_p3;
                w = __int_as_float(__builtin_amdgcn_ds_bpermute(addr, __float_as_int(src)));
            }
#pragma unroll
            for (int k = 0; k < 8; ++k) {
                const int jj = k + 24 - o;
                if (jj >= 0 && jj < KLEN)
                    acc[k] = fmaf(kt[jj], w, acc[k]);
            }
        }

        // ---- candidates (exact reference arithmetic) ----
        const int tb = b * BLK + 8 * lane;
        int cand[8];
#pragma unroll
        for (int k = 0; k < 8; ++k) {
            float vfree = v_reset + acc[k] / 100.0f;   // true IEEE divide
            cand[k] = (vfree >= v_th) ? 1 : 0;
        }
        cand[0] &= (tb != 0);   // spikes[0] forced 0 (loop starts at t=1)

        const int cm = cand[0] | cand[1] | cand[2] | cand[3]
                     | cand[4] | cand[5] | cand[6] | cand[7];
        const unsigned long long anyc = __ballot(cm != 0);

        float4 o0, o1;
        if (anyc == 0ULL) {
            // No threshold crossing anywhere in this 512-block: spikes are all
            // zero regardless of incoming state, and any refractory countdown
            // (<=3) expires within the block.
            o0.x = o0.y = o0.z = o0.w = 0.0f;
            o1.x = o1.y = o1.z = o1.w = 0.0f;
            r0 = 0;
        } else {
            // ---- per-lane 8-step transfer map for incoming ref in {0..3} ----
            int s0 = 0, s1 = 1, s2 = 2, s3 = 3;
#pragma unroll
            for (int k = 0; k < 8; ++k) {
                const int c3 = cand[k] ? 3 : 0;
                s0 = (s0 > 0) ? (s0 - 1) : c3;
                s1 = (s1 > 0) ? (s1 - 1) : c3;
                s2 = (s2 > 0) ? (s2 - 1) : c3;
                s3 = (s3 > 0) ? (s3 - 1) : c3;
            }
            int P = s0 | (s1 << 2) | (s2 << 4) | (s3 << 6);

            // ---- inclusive prefix composition across 64 lanes ----
#pragma unroll
            for (int d = 1; d < 64; d <<= 1) {
                const int prev = __shfl_up(P, d, 64);
                const int comp = map_compose(prev, P);
                P = (lane >= d) ? comp : P;
            }
            const int Pprev = __shfl_up(P, 1, 64);
            const int sin0  = (lane == 0) ? r0 : ((Pprev >> (2 * r0)) & 3);
            const int Pfull = __shfl(P, 63, 64);
            r0 = (Pfull >> (2 * r0)) & 3;   // carry to next 512-block

            // ---- replay with true incoming state ----
            int s = sin0;
            float sp[8];
#pragma unroll
            for (int k = 0; k < 8; ++k) {
                const int spike = (s == 0) & cand[k];
                sp[k] = spike ? 1.0f : 0.0f;
                s = (s > 0) ? (s - 1) : (cand[k] ? 3 : 0);
            }
            o0.x = sp[0]; o0.y = sp[1]; o0.z = sp[2]; o0.w = sp[3];
            o1.x = sp[4]; o1.y = sp[5]; o1.z = sp[6]; o1.w = sp[7];
        }

        float4* dst = (float4*)(Orow + tb);
        dst[0] = o0; dst[1] = o1;

        // ---- rotate register sets ----
#pragma unroll
        for (int j = 0; j < 8; ++j) { Pv[j] = Cv[j]; Cv[j] = Nv[j]; Nv[j] = Lv[j]; }
    }
}

extern "C" void kernel_launch(void* const* d_in, const int* in_sizes, int n_in,
                              void* d_out, int out_size, void* d_ws, size_t ws_size,
                              hipStream_t stream) {
    const float* I       = (const float*)d_in[0];
    const float* tau_m   = (const float*)d_in[1];
    const float* tau_s   = (const float*)d_in[2];
    const float* v_th    = (const float*)d_in[3];
    const float* v_reset = (const float*)d_in[4];
    float* out = (float*)d_out;

    srm_kernel<<<dim3(NROWS / WPB), dim3(256), 0, stream>>>(
        I, tau_m, tau_s, v_th, v_reset, out);
}